// Round 9
// baseline (238.973 us; speedup 1.0000x reference)
//
#include <hip/hip_runtime.h>
#include <hip/hip_bf16.h>
#include <math.h>

// Problem constants: N=4, E=64, L=512, D=768
#define PN 4
#define PE 64
#define PL 512
#define PD 768
#define PK2 (2 * PD)        // 1536
#define PM (PN * PE)        // 256 rows

#define EG 4                // entities per pool block
#define DCW 128             // d-columns per pool block
#define NDC (PD / DCW)      // 6 d-chunks
#define NPOOLB (PN * (PE / EG) * NDC)   // 384 pool blocks
#define NCVT 288            // W-convert blocks (288*512*8 = PD*PK2)
#define NGRID 768           // total blocks = GEMM tiles (1:1)

using bf16x8 = __attribute__((ext_vector_type(8))) short;
using f32x4  = __attribute__((ext_vector_type(4))) float;

static __device__ __forceinline__ unsigned short f2bf(float x) {
    unsigned int u = __float_as_uint(x);
    unsigned int r = (u + 0x7FFFu + ((u >> 16) & 1u)) >> 16;   // RNE
    return (unsigned short)r;
}

// ---------------------------------------------------------------------------
// fused_pc: ONE launch, manual producer-consumer sync via device-scope
// atomic counter (no cooperative grid.sync -- measured 55us, rejected R8).
// 768 blocks x 512 thr, __launch_bounds__(512,6) -> 3 blocks/CU guaranteed
// co-resident (24 waves/CU <= 32; 96KB LDS <= 160; VGPR capped) -> spin is
// deadlock-free by capacity arithmetic.
//   Produce: blocks 0..383 pool (R7 math, exact reference semantics);
//            blocks 384..671 convert W->bf16; 672..767 nothing.
//   Sync:    __threadfence + release atomicAdd; tid0 spins (acquire) to 768.
//   Consume: block bid computes GEMM tile bid: 8-wave K-split (192 each,
//            6 MFMA), LDS reduce, out = Pb x Wb^T + bias.
// ---------------------------------------------------------------------------
__global__ __launch_bounds__(512, 6) void fused_pc(
    const float* __restrict__ doc,    // [N][L][D]
    const float* __restrict__ map,    // [N][E][L]
    const float* __restrict__ lens,   // [N][E]
    const float* __restrict__ W,      // [768][1536]
    const float* __restrict__ b,      // [768]
    unsigned short* __restrict__ Pb,  // [256][1536] bf16
    unsigned short* __restrict__ Wb,  // [768][1536] bf16
    unsigned int*  __restrict__ cnt,  // ready counter (memset to 0 pre-launch)
    float* __restrict__ out)          // [256][768]
{
    __shared__ union {
        struct { float2 lmax[8][EG][64]; float2 lsum[8][EG][64]; } pool; // 32 KB
        f32x4 racc[8][64];                                               // 8 KB
    } sh;

    const int bid  = blockIdx.x;
    const int tid  = threadIdx.x;
    const int w    = tid >> 6;
    const int lane = tid & 63;

    // ---------------- Produce ----------------
    if (bid < NPOOLB) {
        // pool (n, e-group of 4, d-chunk of 128); 8 waves x 64 l each
        const int dc   = bid % NDC;
        const int rest = bid / NDC;
        const int eg   = rest & 15;
        const int n    = rest >> 4;
        const int e0   = eg * EG;
        const int d0   = dc * DCW;

        unsigned long long mk[EG];
        #pragma unroll
        for (int e = 0; e < EG; ++e) {
            const float m = map[((size_t)n * PE + e0 + e) * PL + w * 64 + lane];
            mk[e] = __ballot(m != 0.0f);
        }

        const float2* docp = reinterpret_cast<const float2*>(
            doc + ((size_t)n * PL + w * 64) * PD + d0) + lane;

        float2 mx[EG], sm[EG];
        #pragma unroll
        for (int e = 0; e < EG; ++e) {
            mx[e] = make_float2(-INFINITY, -INFINITY);
            sm[e] = make_float2(0.f, 0.f);
        }

        #pragma unroll 8
        for (int l = 0; l < 64; ++l) {
            const float2 v = docp[(size_t)l * (PD / 2)];
            #pragma unroll
            for (int e = 0; e < EG; ++e) {
                const bool bit = (mk[e] >> l) & 1ull;   // wave-uniform
                const float cx = bit ? v.x : 0.0f;      // exact entity_states elem
                const float cy = bit ? v.y : 0.0f;
                sm[e].x += cx;  sm[e].y += cy;
                mx[e].x = fmaxf(mx[e].x, cx);
                mx[e].y = fmaxf(mx[e].y, cy);
            }
        }

        #pragma unroll
        for (int e = 0; e < EG; ++e) {
            sh.pool.lmax[w][e][lane] = mx[e];
            sh.pool.lsum[w][e][lane] = sm[e];
        }
        __syncthreads();

        const int slot = tid & 255;
        const int e  = slot >> 6;
        const int ln = slot & 63;
        const int ne = n * PE + e0 + e;
        if (tid < 256) {
            float2 m = sh.pool.lmax[0][e][ln];
            #pragma unroll
            for (int ww = 1; ww < 8; ++ww) {
                const float2 t = sh.pool.lmax[ww][e][ln];
                m.x = fmaxf(m.x, t.x);
                m.y = fmaxf(m.y, t.y);
            }
            const unsigned int pk = (unsigned int)f2bf(m.x) | ((unsigned int)f2bf(m.y) << 16);
            *reinterpret_cast<unsigned int*>(Pb + (size_t)ne * PK2 + d0 + ln * 2) = pk;
        } else {
            float2 s = sh.pool.lsum[0][e][ln];
            #pragma unroll
            for (int ww = 1; ww < 8; ++ww) {
                const float2 t = sh.pool.lsum[ww][e][ln];
                s.x += t.x;
                s.y += t.y;
            }
            const float inv = 1.0f / lens[ne];
            const unsigned int pk = (unsigned int)f2bf(s.x * inv) | ((unsigned int)f2bf(s.y * inv) << 16);
            *reinterpret_cast<unsigned int*>(Pb + (size_t)ne * PK2 + PD + d0 + ln * 2) = pk;
        }
    } else if (bid < NPOOLB + NCVT) {
        // W conversion
        const size_t i = ((size_t)(bid - NPOOLB) * 512 + tid) * 8;
        const float4 a = *reinterpret_cast<const float4*>(W + i);
        const float4 c = *reinterpret_cast<const float4*>(W + i + 4);
        union { unsigned short s[8]; uint4 v; } r;
        r.s[0] = f2bf(a.x); r.s[1] = f2bf(a.y); r.s[2] = f2bf(a.z); r.s[3] = f2bf(a.w);
        r.s[4] = f2bf(c.x); r.s[5] = f2bf(c.y); r.s[6] = f2bf(c.z); r.s[7] = f2bf(c.w);
        *reinterpret_cast<uint4*>(Wb + i) = r.v;
    }

    // ---------------- Sync: release-add, then spin ----------------
    __syncthreads();                    // all block writes issued (also closes LDS WAR)
    if (tid == 0) {
        __threadfence();                // device-scope release (writeback)
        __hip_atomic_fetch_add(cnt, 1u, __ATOMIC_RELAXED, __HIP_MEMORY_SCOPE_AGENT);
        while (__hip_atomic_load(cnt, __ATOMIC_ACQUIRE, __HIP_MEMORY_SCOPE_AGENT) < (unsigned)NGRID) {
            __builtin_amdgcn_s_sleep(8);
        }
    }
    __syncthreads();
    __threadfence();                    // acquire side: invalidate stale caches

    // ---------------- Consume: GEMM tile = bid ----------------
    {
        const int tile = bid;                    // 0..767
        const int rt = tile & 15;                // M tile
        const int ct = tile >> 4;                // N tile
        const int r0 = rt * 16, d0 = ct * 16;

        const int fr = lane & 15;
        const int kg = lane >> 4;
        const int kb = w * (PK2 / 8);            // 192-wide K slice per wave

        const unsigned short* pA = Pb + (size_t)(r0 + fr) * PK2 + kb + kg * 8;
        const unsigned short* pB = Wb + (size_t)(d0 + fr) * PK2 + kb + kg * 8;

        f32x4 acc = {0.f, 0.f, 0.f, 0.f};
        #pragma unroll
        for (int k0 = 0; k0 < PK2 / 8; k0 += 32) {
            const bf16x8 a  = *reinterpret_cast<const bf16x8*>(pA + k0);
            const bf16x8 bb = *reinterpret_cast<const bf16x8*>(pB + k0);
            acc = __builtin_amdgcn_mfma_f32_16x16x32_bf16(a, bb, acc, 0, 0, 0);
        }

        sh.racc[w][lane] = acc;
        __syncthreads();

        if (w == 0) {
            f32x4 a = sh.racc[0][lane];
            #pragma unroll
            for (int ww = 1; ww < 8; ++ww) a += sh.racc[ww][lane];
            const int c = d0 + fr;
            const float bias = b[c];
            #pragma unroll
            for (int j = 0; j < 4; ++j)
                out[(size_t)(r0 + kg * 4 + j) * PD + c] = a[j] + bias;
        }
    }
}

// ===========================================================================
// Fallback path = R7 (proven, 30.4 us): pool_full + gemm_mfma1
// ===========================================================================
__global__ __launch_bounds__(512) void pool_full(
    const float* __restrict__ doc, const float* __restrict__ map,
    const float* __restrict__ lens, const float* __restrict__ W,
    unsigned short* __restrict__ Pb, unsigned short* __restrict__ Wb)
{
    const int bid = blockIdx.x;
    const int tid = threadIdx.x;

    if (bid >= NPOOLB) {
        const size_t i = ((size_t)(bid - NPOOLB) * 512 + tid) * 8;
        const float4 a = *reinterpret_cast<const float4*>(W + i);
        const float4 c = *reinterpret_cast<const float4*>(W + i + 4);
        union { unsigned short s[8]; uint4 v; } r;
        r.s[0] = f2bf(a.x); r.s[1] = f2bf(a.y); r.s[2] = f2bf(a.z); r.s[3] = f2bf(a.w);
        r.s[4] = f2bf(c.x); r.s[5] = f2bf(c.y); r.s[6] = f2bf(c.z); r.s[7] = f2bf(c.w);
        *reinterpret_cast<uint4*>(Wb + i) = r.v;
        return;
    }

    __shared__ float2 lmax[8][EG][64];
    __shared__ float2 lsum[8][EG][64];

    const int dc   = bid % NDC;
    const int rest = bid / NDC;
    const int eg   = rest & 15;
    const int n    = rest >> 4;
    const int e0   = eg * EG;
    const int d0   = dc * DCW;
    const int w    = tid >> 6;
    const int lane = tid & 63;

    unsigned long long mk[EG];
    #pragma unroll
    for (int e = 0; e < EG; ++e) {
        const float m = map[((size_t)n * PE + e0 + e) * PL + w * 64 + lane];
        mk[e] = __ballot(m != 0.0f);
    }

    const float2* docp = reinterpret_cast<const float2*>(
        doc + ((size_t)n * PL + w * 64) * PD + d0) + lane;

    float2 mx[EG], sm[EG];
    #pragma unroll
    for (int e = 0; e < EG; ++e) {
        mx[e] = make_float2(-INFINITY, -INFINITY);
        sm[e] = make_float2(0.f, 0.f);
    }

    #pragma unroll 8
    for (int l = 0; l < 64; ++l) {
        const float2 v = docp[(size_t)l * (PD / 2)];
        #pragma unroll
        for (int e = 0; e < EG; ++e) {
            const bool bit = (mk[e] >> l) & 1ull;
            const float cx = bit ? v.x : 0.0f;
            const float cy = bit ? v.y : 0.0f;
            sm[e].x += cx;  sm[e].y += cy;
            mx[e].x = fmaxf(mx[e].x, cx);
            mx[e].y = fmaxf(mx[e].y, cy);
        }
    }

    #pragma unroll
    for (int e = 0; e < EG; ++e) {
        lmax[w][e][lane] = mx[e];
        lsum[w][e][lane] = sm[e];
    }
    __syncthreads();

    const int slot = tid & 255;
    const int e  = slot >> 6;
    const int ln = slot & 63;
    const int ne = n * PE + e0 + e;
    if (tid < 256) {
        float2 m = lmax[0][e][ln];
        #pragma unroll
        for (int ww = 1; ww < 8; ++ww) {
            const float2 t = lmax[ww][e][ln];
            m.x = fmaxf(m.x, t.x);
            m.y = fmaxf(m.y, t.y);
        }
        const unsigned int pk = (unsigned int)f2bf(m.x) | ((unsigned int)f2bf(m.y) << 16);
        *reinterpret_cast<unsigned int*>(Pb + (size_t)ne * PK2 + d0 + ln * 2) = pk;
    } else {
        float2 s = lsum[0][e][ln];
        #pragma unroll
        for (int ww = 1; ww < 8; ++ww) {
            const float2 t = lsum[ww][e][ln];
            s.x += t.x;
            s.y += t.y;
        }
        const float inv = 1.0f / lens[ne];
        const unsigned int pk = (unsigned int)f2bf(s.x * inv) | ((unsigned int)f2bf(s.y * inv) << 16);
        *reinterpret_cast<unsigned int*>(Pb + (size_t)ne * PK2 + PD + d0 + ln * 2) = pk;
    }
}

__global__ __launch_bounds__(64) void gemm_mfma1(
    const unsigned short* __restrict__ Pb, const unsigned short* __restrict__ Wb,
    const float* __restrict__ b, float* __restrict__ out)
{
    const int lane = threadIdx.x;
    const int tile = blockIdx.x;
    const int rt = tile & 15, ct = tile >> 4;
    const int r0 = rt * 16, d0 = ct * 16;
    const int fr = lane & 15, kg = lane >> 4;
    const unsigned short* pA = Pb + (size_t)(r0 + fr) * PK2 + kg * 8;
    const unsigned short* pB = Wb + (size_t)(d0 + fr) * PK2 + kg * 8;
    f32x4 acc = {0.f, 0.f, 0.f, 0.f};
    #pragma unroll 8
    for (int k0 = 0; k0 < PK2; k0 += 32) {
        const bf16x8 a  = *reinterpret_cast<const bf16x8*>(pA + k0);
        const bf16x8 bb = *reinterpret_cast<const bf16x8*>(pB + k0);
        acc = __builtin_amdgcn_mfma_f32_16x16x32_bf16(a, bb, acc, 0, 0, 0);
    }
    const int c = d0 + fr;
    const float bias = b[c];
    #pragma unroll
    for (int j = 0; j < 4; ++j)
        out[(size_t)(r0 + kg * 4 + j) * PD + c] = acc[j] + bias;
}

__global__ __launch_bounds__(256) void fused_kernel(
    const float* __restrict__ doc, const float* __restrict__ map,
    const float* __restrict__ lens, const float* __restrict__ W,
    const float* __restrict__ b, float* __restrict__ out)
{
    __shared__ float Prow[PK2];
    const int ne = blockIdx.x, n = ne >> 6, t = threadIdx.x;
    const float* docn = doc + (size_t)n * PL * PD;
    const float* mrow = map + (size_t)ne * PL;
    float mx0=-INFINITY, mx1=-INFINITY, mx2=-INFINITY, s0=0.f, s1=0.f, s2=0.f;
    bool has_zero = false;
    for (int l = 0; l < PL; ++l) {
        const float m = mrow[l];
        if (m != 0.0f) {
            const float* dr = docn + (size_t)l * PD;
            const float a = dr[t], c = dr[t+256], e = dr[t+512];
            mx0=fmaxf(mx0,a); s0+=a; mx1=fmaxf(mx1,c); s1+=c; mx2=fmaxf(mx2,e); s2+=e;
        } else has_zero = true;
    }
    if (has_zero) { mx0=fmaxf(mx0,0.f); mx1=fmaxf(mx1,0.f); mx2=fmaxf(mx2,0.f); }
    const float invlen = 1.0f / lens[ne];
    Prow[t]=mx0; Prow[t+256]=mx1; Prow[t+512]=mx2;
    Prow[PD+t]=s0*invlen; Prow[PD+t+256]=s1*invlen; Prow[PD+t+512]=s2*invlen;
    __syncthreads();
    #pragma unroll
    for (int i = 0; i < 3; ++i) {
        const int d = t + i*256;
        const float* wrow = W + (size_t)d * PK2;
        float acc = 0.f;
        for (int k = 0; k < PK2; k += 4) {
            const float4 w = *reinterpret_cast<const float4*>(&wrow[k]);
            acc += Prow[k]*w.x + Prow[k+1]*w.y + Prow[k+2]*w.z + Prow[k+3]*w.w;
        }
        out[(size_t)ne * PD + d] = acc + b[d];
    }
}

extern "C" void kernel_launch(void* const* d_in, const int* in_sizes, int n_in,
                              void* d_out, int out_size, void* d_ws, size_t ws_size,
                              hipStream_t stream) {
    const float* doc  = (const float*)d_in[0];   // (4,512,768)
    const float* map  = (const float*)d_in[1];   // (4,64,512)
    const float* lens = (const float*)d_in[2];   // (4,64)
    const float* W    = (const float*)d_in[3];   // (768,1536)
    const float* b    = (const float*)d_in[4];   // (768,)
    float* out = (float*)d_out;                  // (4,64,768)

    const size_t pb_bytes  = (size_t)PM * PK2 * sizeof(unsigned short);  // 768 KiB
    const size_t wb_bytes  = (size_t)PD * PK2 * sizeof(unsigned short);  // 2.25 MiB
    const size_t cnt_off   = 4u * 1024u * 1024u;                         // 4 MiB mark
    const size_t need_pc   = cnt_off + 128;
    const size_t need_r7   = pb_bytes + wb_bytes;                        // 3 MiB

    if (ws_size >= need_pc) {
        unsigned short* Pb = (unsigned short*)d_ws;
        unsigned short* Wb = (unsigned short*)((char*)d_ws + pb_bytes);
        unsigned int* cnt  = (unsigned int*)((char*)d_ws + cnt_off);
        hipError_t e = hipMemsetAsync((void*)cnt, 0, sizeof(unsigned int), stream);
        if (e == hipSuccess) {
            fused_pc<<<dim3(NGRID), dim3(512), 0, stream>>>(
                doc, map, lens, W, b, Pb, Wb, cnt, out);
            return;
        }
        (void)hipGetLastError();
        // fall through to R7 path
    }

    if (ws_size >= need_r7) {
        unsigned short* Pb = (unsigned short*)d_ws;
        unsigned short* Wb = (unsigned short*)((char*)d_ws + pb_bytes);
        pool_full<<<dim3(NPOOLB + NCVT), dim3(512), 0, stream>>>(
            doc, map, lens, W, Pb, Wb);
        gemm_mfma1<<<dim3((PM / 16) * (PD / 16)), dim3(64), 0, stream>>>(Pb, Wb, b, out);
    } else {
        fused_kernel<<<dim3(PM), dim3(256), 0, stream>>>(doc, map, lens, W, b, out);
    }
}

// Round 10
// 30.474 us; speedup vs baseline: 7.8419x; 7.8419x over previous
//
#include <hip/hip_runtime.h>
#include <hip/hip_bf16.h>
#include <math.h>

// Problem constants: N=4, E=64, L=512, D=768
#define PN 4
#define PE 64
#define PL 512
#define PD 768
#define PK2 (2 * PD)        // 1536
#define PM (PN * PE)        // 256 rows

#define EG 4                // entities per pool block
#define DCW 64              // d-columns per pool block (1 f32 per lane)
#define NDC (PD / DCW)      // 12 d-chunks
#define NPOOLB (PN * (PE / EG) * NDC)   // 768 pool blocks
#define NCVT 288            // W-convert blocks (288*512*8 = PD*PK2)

using bf16x8 = __attribute__((ext_vector_type(8))) short;
using f32x4  = __attribute__((ext_vector_type(4))) float;

static __device__ __forceinline__ unsigned short f2bf(float x) {
    unsigned int u = __float_as_uint(x);
    unsigned int r = (u + 0x7FFFu + ((u >> 16) & 1u)) >> 16;   // RNE
    return (unsigned short)r;
}

// ---------------------------------------------------------------------------
// pool_v5: 768 pool blocks + 288 fused W-convert blocks, 512 threads.
// Pool block = (n, e-group of 4, d-chunk of 64). 8 waves; wave w owns
// l in [w*64, w*64+64) -> all of L covered in-block. Lane owns ONE d column.
// Masks: one 64-bit ballot per (wave, entity) -> SGPR.
// Per (l,e):  s_mval = bit ? 1.0 : 0.0  (SALU s_cselect, no vcc!)
//             cand = s_mval * v   (v_mul with SGPR operand -- EXACTLY the
//             reference's mask*doc elementwise product, incl. +/-0)
//             sm += cand; mx = fmax(mx, cand)
// Cross-wave reduce via 16 KB LDS; writes Pb bf16 [256][1536] (max | mean).
// ---------------------------------------------------------------------------
__global__ __launch_bounds__(512) void pool_v5(
    const float* __restrict__ doc,    // [N][L][D]
    const float* __restrict__ map,    // [N][E][L]
    const float* __restrict__ lens,   // [N][E]
    const float* __restrict__ W,      // [768][1536]
    unsigned short* __restrict__ Pb,  // [256][1536] bf16
    unsigned short* __restrict__ Wb)  // [768][1536] bf16
{
    const int bid = blockIdx.x;
    const int tid = threadIdx.x;

    if (bid >= NPOOLB) {
        // ---- W conversion blocks ----
        const size_t i = ((size_t)(bid - NPOOLB) * 512 + tid) * 8;
        const float4 a = *reinterpret_cast<const float4*>(W + i);
        const float4 c = *reinterpret_cast<const float4*>(W + i + 4);
        union { unsigned short s[8]; uint4 v; } r;
        r.s[0] = f2bf(a.x); r.s[1] = f2bf(a.y); r.s[2] = f2bf(a.z); r.s[3] = f2bf(a.w);
        r.s[4] = f2bf(c.x); r.s[5] = f2bf(c.y); r.s[6] = f2bf(c.z); r.s[7] = f2bf(c.w);
        *reinterpret_cast<uint4*>(Wb + i) = r.v;
        return;
    }

    __shared__ float lmax[8][EG][64];   // 8 KB
    __shared__ float lsum[8][EG][64];   // 8 KB

    const int dc   = bid % NDC;
    const int rest = bid / NDC;
    const int eg   = rest & 15;          // 16 e-groups
    const int n    = rest >> 4;
    const int e0   = eg * EG;
    const int d0   = dc * DCW;
    const int w    = tid >> 6;
    const int lane = tid & 63;

    // per-wave 64-bit masks for its own l-window (wave-uniform SGPR)
    unsigned long long mk[EG];
    #pragma unroll
    for (int e = 0; e < EG; ++e) {
        const float m = map[((size_t)n * PE + e0 + e) * PL + w * 64 + lane];
        mk[e] = __ballot(m != 0.0f);
    }

    const float* docp = doc + ((size_t)n * PL + w * 64) * PD + d0 + lane;

    float mx[EG], sm[EG];
    #pragma unroll
    for (int e = 0; e < EG; ++e) { mx[e] = -INFINITY; sm[e] = 0.f; }

    #pragma unroll 16
    for (int l = 0; l < 64; ++l) {
        const float v = docp[(size_t)l * PD];
        #pragma unroll
        for (int e = 0; e < EG; ++e) {
            const float mval = ((mk[e] >> l) & 1ull) ? 1.0f : 0.0f;  // s_cselect
            const float cand = mval * v;      // == reference mask*doc elem
            sm[e] += cand;
            mx[e] = fmaxf(mx[e], cand);
        }
    }

    #pragma unroll
    for (int e = 0; e < EG; ++e) {
        lmax[w][e][lane] = mx[e];
        lsum[w][e][lane] = sm[e];
    }
    __syncthreads();

    // 256 (e,ln) slots; tid<256 -> max, tid>=256 -> mean
    const int slot = tid & 255;
    const int e  = slot >> 6;
    const int ln = slot & 63;
    const int ne = n * PE + e0 + e;
    const int d  = d0 + ln;
    if (tid < 256) {
        float m = lmax[0][e][ln];
        #pragma unroll
        for (int ww = 1; ww < 8; ++ww) m = fmaxf(m, lmax[ww][e][ln]);
        Pb[(size_t)ne * PK2 + d] = f2bf(m);
    } else {
        float s = lsum[0][e][ln];
        #pragma unroll
        for (int ww = 1; ww < 8; ++ww) s += lsum[ww][e][ln];
        Pb[(size_t)ne * PK2 + PD + d] = f2bf(s * (1.0f / lens[ne]));
    }
}

// ---------------------------------------------------------------------------
// gemm_ks2: MFMA bf16 16x16x32, K split 2 ways across 2 waves, 2 accumulators
// per wave for ILP. 768 blocks x 128 thr; out = Pb x Wb^T + bias.
// ---------------------------------------------------------------------------
__global__ __launch_bounds__(128) void gemm_ks2(
    const unsigned short* __restrict__ Pb,  // [256][1536] bf16
    const unsigned short* __restrict__ Wb,  // [768][1536] bf16
    const float* __restrict__ b,            // [768]
    float* __restrict__ out)                // [256][768]
{
    __shared__ f32x4 red[64];

    const int w    = threadIdx.x >> 6;
    const int lane = threadIdx.x & 63;
    const int tile = blockIdx.x;             // 0..767
    const int rt = tile & 15;                // M tile
    const int ct = tile >> 4;                // N tile
    const int r0 = rt * 16, d0 = ct * 16;

    const int fr = lane & 15;
    const int kg = lane >> 4;
    const int kb = w * (PK2 / 2);            // 768-wide K slice per wave

    const unsigned short* pA = Pb + (size_t)(r0 + fr) * PK2 + kb + kg * 8;
    const unsigned short* pB = Wb + (size_t)(d0 + fr) * PK2 + kb + kg * 8;

    f32x4 acc0 = {0.f, 0.f, 0.f, 0.f};
    f32x4 acc1 = {0.f, 0.f, 0.f, 0.f};
    #pragma unroll
    for (int k0 = 0; k0 < PK2 / 2; k0 += 64) {
        const bf16x8 a0 = *reinterpret_cast<const bf16x8*>(pA + k0);
        const bf16x8 b0 = *reinterpret_cast<const bf16x8*>(pB + k0);
        acc0 = __builtin_amdgcn_mfma_f32_16x16x32_bf16(a0, b0, acc0, 0, 0, 0);
        const bf16x8 a1 = *reinterpret_cast<const bf16x8*>(pA + k0 + 32);
        const bf16x8 b1 = *reinterpret_cast<const bf16x8*>(pB + k0 + 32);
        acc1 = __builtin_amdgcn_mfma_f32_16x16x32_bf16(a1, b1, acc1, 0, 0, 0);
    }
    f32x4 acc = acc0 + acc1;

    if (w == 1) red[lane] = acc;
    __syncthreads();
    if (w == 0) {
        acc += red[lane];
        const int c = d0 + fr;
        const float bias = b[c];
        #pragma unroll
        for (int j = 0; j < 4; ++j)
            out[(size_t)(r0 + kg * 4 + j) * PD + c] = acc[j] + bias;
    }
}

// ===========================================================================
// Fallback: fully fused f32 (R1-proven) -- used only if ws is tiny.
// ===========================================================================
__global__ __launch_bounds__(256) void fused_kernel(
    const float* __restrict__ doc, const float* __restrict__ map,
    const float* __restrict__ lens, const float* __restrict__ W,
    const float* __restrict__ b, float* __restrict__ out)
{
    __shared__ float Prow[PK2];
    const int ne = blockIdx.x, n = ne >> 6, t = threadIdx.x;
    const float* docn = doc + (size_t)n * PL * PD;
    const float* mrow = map + (size_t)ne * PL;
    float mx0=-INFINITY, mx1=-INFINITY, mx2=-INFINITY, s0=0.f, s1=0.f, s2=0.f;
    bool has_zero = false;
    for (int l = 0; l < PL; ++l) {
        const float m = mrow[l];
        if (m != 0.0f) {
            const float* dr = docn + (size_t)l * PD;
            const float a = dr[t], c = dr[t+256], e = dr[t+512];
            mx0=fmaxf(mx0,a); s0+=a; mx1=fmaxf(mx1,c); s1+=c; mx2=fmaxf(mx2,e); s2+=e;
        } else has_zero = true;
    }
    if (has_zero) { mx0=fmaxf(mx0,0.f); mx1=fmaxf(mx1,0.f); mx2=fmaxf(mx2,0.f); }
    const float invlen = 1.0f / lens[ne];
    Prow[t]=mx0; Prow[t+256]=mx1; Prow[t+512]=mx2;
    Prow[PD+t]=s0*invlen; Prow[PD+t+256]=s1*invlen; Prow[PD+t+512]=s2*invlen;
    __syncthreads();
    #pragma unroll
    for (int i = 0; i < 3; ++i) {
        const int d = t + i*256;
        const float* wrow = W + (size_t)d * PK2;
        float acc = 0.f;
        for (int k = 0; k < PK2; k += 4) {
            const float4 w = *reinterpret_cast<const float4*>(&wrow[k]);
            acc += Prow[k]*w.x + Prow[k+1]*w.y + Prow[k+2]*w.z + Prow[k+3]*w.w;
        }
        out[(size_t)ne * PD + d] = acc + b[d];
    }
}

extern "C" void kernel_launch(void* const* d_in, const int* in_sizes, int n_in,
                              void* d_out, int out_size, void* d_ws, size_t ws_size,
                              hipStream_t stream) {
    const float* doc  = (const float*)d_in[0];   // (4,512,768)
    const float* map  = (const float*)d_in[1];   // (4,64,512)
    const float* lens = (const float*)d_in[2];   // (4,64)
    const float* W    = (const float*)d_in[3];   // (768,1536)
    const float* b    = (const float*)d_in[4];   // (768,)
    float* out = (float*)d_out;                  // (4,64,768)

    const size_t pb_bytes = (size_t)PM * PK2 * sizeof(unsigned short);   // 768 KiB
    const size_t wb_bytes = (size_t)PD * PK2 * sizeof(unsigned short);   // 2.25 MiB
    const size_t need     = pb_bytes + wb_bytes;                         // 3 MiB

    if (ws_size >= need) {
        unsigned short* Pb = (unsigned short*)d_ws;
        unsigned short* Wb = (unsigned short*)((char*)d_ws + pb_bytes);
        pool_v5<<<dim3(NPOOLB + NCVT), dim3(512), 0, stream>>>(
            doc, map, lens, W, Pb, Wb);
        gemm_ks2<<<dim3((PM / 16) * (PD / 16)), dim3(128), 0, stream>>>(Pb, Wb, b, out);
    } else {
        fused_kernel<<<dim3(PM), dim3(256), 0, stream>>>(doc, map, lens, W, b, out);
    }
}

// Round 11
// 28.599 us; speedup vs baseline: 8.3559x; 1.0655x over previous
//
#include <hip/hip_runtime.h>
#include <hip/hip_bf16.h>
#include <math.h>

// Problem constants: N=4, E=64, L=512, D=768
#define PN 4
#define PE 64
#define PL 512
#define PD 768
#define PK2 (2 * PD)        // 1536
#define PM (PN * PE)        // 256 rows

#define EG 4                // entities per pool block
#define DCW 64              // d-columns per pool block (1 f32 per lane)
#define NDC (PD / DCW)      // 12 d-chunks
#define NPOOLB (PN * (PE / EG) * NDC)   // 768 pool blocks
#define NCVT 288            // W-convert blocks (288*512*8 = PD*PK2)
#define NXCD 8

using bf16x8 = __attribute__((ext_vector_type(8))) short;
using f32x4  = __attribute__((ext_vector_type(4))) float;

static __device__ __forceinline__ unsigned short f2bf(float x) {
    unsigned int u = __float_as_uint(x);
    unsigned int r = (u + 0x7FFFu + ((u >> 16) & 1u)) >> 16;   // RNE
    return (unsigned short)r;
}

// ---------------------------------------------------------------------------
// pool_v6: identical math to pool_v5 (R10), but XCD-aware work mapping.
// Hardware round-robins blockIdx across 8 XCDs (bid & 7 = XCD). We assign:
//   XCD x -> n = x>>1, d-half = x&1. Per-XCD doc working set = 512*384*4B
//   = 768 KB -> L2-resident; the 16x entity-group re-reads hit L2, not L3.
// Per XCD: 132 slots (bid>>3): 0..95 = pool (eg = s/6, dc = dhalf*6 + s%6),
//          96..131 = W-convert (this XCD converts its 1/8 stripe of W).
// ---------------------------------------------------------------------------
__global__ __launch_bounds__(512) void pool_v6(
    const float* __restrict__ doc,    // [N][L][D]
    const float* __restrict__ map,    // [N][E][L]
    const float* __restrict__ lens,   // [N][E]
    const float* __restrict__ W,      // [768][1536]
    unsigned short* __restrict__ Pb,  // [256][1536] bf16
    unsigned short* __restrict__ Wb)  // [768][1536] bf16
{
    const int bid = blockIdx.x;
    const int tid = threadIdx.x;
    const int xcd = bid & (NXCD - 1);   // target XCD under round-robin
    const int idx = bid >> 3;           // 0..131 within XCD

    if (idx >= 96) {
        // ---- W conversion: XCD-local stripe of W ----
        const int ci = xcd * 36 + (idx - 96);           // 0..287
        const size_t i = ((size_t)ci * 512 + tid) * 8;
        const float4 a = *reinterpret_cast<const float4*>(W + i);
        const float4 c = *reinterpret_cast<const float4*>(W + i + 4);
        union { unsigned short s[8]; uint4 v; } r;
        r.s[0] = f2bf(a.x); r.s[1] = f2bf(a.y); r.s[2] = f2bf(a.z); r.s[3] = f2bf(a.w);
        r.s[4] = f2bf(c.x); r.s[5] = f2bf(c.y); r.s[6] = f2bf(c.z); r.s[7] = f2bf(c.w);
        *reinterpret_cast<uint4*>(Wb + i) = r.v;
        return;
    }

    __shared__ float lmax[8][EG][64];   // 8 KB
    __shared__ float lsum[8][EG][64];   // 8 KB

    const int n   = xcd >> 1;            // XCD pair owns one n
    const int dh  = xcd & 1;             // d-half
    const int eg  = idx / 6;             // 0..15
    const int dc  = dh * 6 + (idx % 6);  // 0..11
    const int e0  = eg * EG;
    const int d0  = dc * DCW;
    const int w    = tid >> 6;
    const int lane = tid & 63;

    // per-wave 64-bit masks for its own l-window (wave-uniform SGPR)
    unsigned long long mk[EG];
    #pragma unroll
    for (int e = 0; e < EG; ++e) {
        const float m = map[((size_t)n * PE + e0 + e) * PL + w * 64 + lane];
        mk[e] = __ballot(m != 0.0f);
    }

    const float* docp = doc + ((size_t)n * PL + w * 64) * PD + d0 + lane;

    float mx[EG], sm[EG];
    #pragma unroll
    for (int e = 0; e < EG; ++e) { mx[e] = -INFINITY; sm[e] = 0.f; }

    #pragma unroll 16
    for (int l = 0; l < 64; ++l) {
        const float v = docp[(size_t)l * PD];
        #pragma unroll
        for (int e = 0; e < EG; ++e) {
            const float mval = ((mk[e] >> l) & 1ull) ? 1.0f : 0.0f;  // s_cselect
            const float cand = mval * v;      // == reference mask*doc elem
            sm[e] += cand;
            mx[e] = fmaxf(mx[e], cand);
        }
    }

    #pragma unroll
    for (int e = 0; e < EG; ++e) {
        lmax[w][e][lane] = mx[e];
        lsum[w][e][lane] = sm[e];
    }
    __syncthreads();

    // 256 (e,ln) slots; tid<256 -> max, tid>=256 -> mean
    const int slot = tid & 255;
    const int e  = slot >> 6;
    const int ln = slot & 63;
    const int ne = n * PE + e0 + e;
    const int d  = d0 + ln;
    if (tid < 256) {
        float m = lmax[0][e][ln];
        #pragma unroll
        for (int ww = 1; ww < 8; ++ww) m = fmaxf(m, lmax[ww][e][ln]);
        Pb[(size_t)ne * PK2 + d] = f2bf(m);
    } else {
        float s = lsum[0][e][ln];
        #pragma unroll
        for (int ww = 1; ww < 8; ++ww) s += lsum[ww][e][ln];
        Pb[(size_t)ne * PK2 + PD + d] = f2bf(s * (1.0f / lens[ne]));
    }
}

// ---------------------------------------------------------------------------
// gemm_ks2x: R10's gemm_ks2 with XCD-aware tile mapping: XCD x owns a
// 6-wide ct stripe (96 douts, W slice 288 KB -> L2-resident; Pb 768 KB fits).
// ---------------------------------------------------------------------------
__global__ __launch_bounds__(128) void gemm_ks2x(
    const unsigned short* __restrict__ Pb,  // [256][1536] bf16
    const unsigned short* __restrict__ Wb,  // [768][1536] bf16
    const float* __restrict__ b,            // [768]
    float* __restrict__ out)                // [256][768]
{
    __shared__ f32x4 red[64];

    const int w    = threadIdx.x >> 6;
    const int lane = threadIdx.x & 63;
    const int bid  = blockIdx.x;
    const int xcd  = bid & (NXCD - 1);
    const int idx  = bid >> 3;               // 0..95
    const int ct = xcd * 6 + (idx >> 4);     // 0..47
    const int rt = idx & 15;                 // 0..15
    const int r0 = rt * 16, d0 = ct * 16;

    const int fr = lane & 15;
    const int kg = lane >> 4;
    const int kb = w * (PK2 / 2);            // 768-wide K slice per wave

    const unsigned short* pA = Pb + (size_t)(r0 + fr) * PK2 + kb + kg * 8;
    const unsigned short* pB = Wb + (size_t)(d0 + fr) * PK2 + kb + kg * 8;

    f32x4 acc0 = {0.f, 0.f, 0.f, 0.f};
    f32x4 acc1 = {0.f, 0.f, 0.f, 0.f};
    #pragma unroll
    for (int k0 = 0; k0 < PK2 / 2; k0 += 64) {
        const bf16x8 a0 = *reinterpret_cast<const bf16x8*>(pA + k0);
        const bf16x8 b0 = *reinterpret_cast<const bf16x8*>(pB + k0);
        acc0 = __builtin_amdgcn_mfma_f32_16x16x32_bf16(a0, b0, acc0, 0, 0, 0);
        const bf16x8 a1 = *reinterpret_cast<const bf16x8*>(pA + k0 + 32);
        const bf16x8 b1 = *reinterpret_cast<const bf16x8*>(pB + k0 + 32);
        acc1 = __builtin_amdgcn_mfma_f32_16x16x32_bf16(a1, b1, acc1, 0, 0, 0);
    }
    f32x4 acc = acc0 + acc1;

    if (w == 1) red[lane] = acc;
    __syncthreads();
    if (w == 0) {
        acc += red[lane];
        const int c = d0 + fr;
        const float bias = b[c];
        #pragma unroll
        for (int j = 0; j < 4; ++j)
            out[(size_t)(r0 + kg * 4 + j) * PD + c] = acc[j] + bias;
    }
}

// ===========================================================================
// Fallback: fully fused f32 (R1-proven) -- used only if ws is tiny.
// ===========================================================================
__global__ __launch_bounds__(256) void fused_kernel(
    const float* __restrict__ doc, const float* __restrict__ map,
    const float* __restrict__ lens, const float* __restrict__ W,
    const float* __restrict__ b, float* __restrict__ out)
{
    __shared__ float Prow[PK2];
    const int ne = blockIdx.x, n = ne >> 6, t = threadIdx.x;
    const float* docn = doc + (size_t)n * PL * PD;
    const float* mrow = map + (size_t)ne * PL;
    float mx0=-INFINITY, mx1=-INFINITY, mx2=-INFINITY, s0=0.f, s1=0.f, s2=0.f;
    bool has_zero = false;
    for (int l = 0; l < PL; ++l) {
        const float m = mrow[l];
        if (m != 0.0f) {
            const float* dr = docn + (size_t)l * PD;
            const float a = dr[t], c = dr[t+256], e = dr[t+512];
            mx0=fmaxf(mx0,a); s0+=a; mx1=fmaxf(mx1,c); s1+=c; mx2=fmaxf(mx2,e); s2+=e;
        } else has_zero = true;
    }
    if (has_zero) { mx0=fmaxf(mx0,0.f); mx1=fmaxf(mx1,0.f); mx2=fmaxf(mx2,0.f); }
    const float invlen = 1.0f / lens[ne];
    Prow[t]=mx0; Prow[t+256]=mx1; Prow[t+512]=mx2;
    Prow[PD+t]=s0*invlen; Prow[PD+t+256]=s1*invlen; Prow[PD+t+512]=s2*invlen;
    __syncthreads();
    #pragma unroll
    for (int i = 0; i < 3; ++i) {
        const int d = t + i*256;
        const float* wrow = W + (size_t)d * PK2;
        float acc = 0.f;
        for (int k = 0; k < PK2; k += 4) {
            const float4 w = *reinterpret_cast<const float4*>(&wrow[k]);
            acc += Prow[k]*w.x + Prow[k+1]*w.y + Prow[k+2]*w.z + Prow[k+3]*w.w;
        }
        out[(size_t)ne * PD + d] = acc + b[d];
    }
}

extern "C" void kernel_launch(void* const* d_in, const int* in_sizes, int n_in,
                              void* d_out, int out_size, void* d_ws, size_t ws_size,
                              hipStream_t stream) {
    const float* doc  = (const float*)d_in[0];   // (4,512,768)
    const float* map  = (const float*)d_in[1];   // (4,64,512)
    const float* lens = (const float*)d_in[2];   // (4,64)
    const float* W    = (const float*)d_in[3];   // (768,1536)
    const float* b    = (const float*)d_in[4];   // (768,)
    float* out = (float*)d_out;                  // (4,64,768)

    const size_t pb_bytes = (size_t)PM * PK2 * sizeof(unsigned short);   // 768 KiB
    const size_t wb_bytes = (size_t)PD * PK2 * sizeof(unsigned short);   // 2.25 MiB
    const size_t need     = pb_bytes + wb_bytes;                         // 3 MiB

    if (ws_size >= need) {
        unsigned short* Pb = (unsigned short*)d_ws;
        unsigned short* Wb = (unsigned short*)((char*)d_ws + pb_bytes);
        pool_v6<<<dim3(NPOOLB + NCVT), dim3(512), 0, stream>>>(
            doc, map, lens, W, Pb, Wb);
        gemm_ks2x<<<dim3((PM / 16) * (PD / 16)), dim3(128), 0, stream>>>(Pb, Wb, b, out);
    } else {
        fused_kernel<<<dim3(PM), dim3(256), 0, stream>>>(doc, map, lens, W, b, out);
    }
}